// Round 14
// baseline (235.063 us; speedup 1.0000x reference)
//
#include <hip/hip_runtime.h>
#include <math.h>

#define N 16384
#define D 1024
#define EPSF 1e-8f
#define QSCALE 448.0f
#define NPAIRS 2080
#define NT 4160 /* tasks = pairs x 2 halves */
#define NBLK 512
#define PANB 262144 /* bytes per 256-row i8 panel */
#define BIAS 16777216u

typedef __attribute__((ext_vector_type(4))) int i32x4;
typedef unsigned int u32;
typedef unsigned long long u64;

// LDS per block: 2 slots x (A 8KB + B 16KB) = 48 KB  -> 2 blocks/CU
#define SLOTB 24576
#define LDS_TOT 49152

__device__ __forceinline__ void gload_lds16(const void* g, void* l) {
  __builtin_amdgcn_global_load_lds(
      (const __attribute__((address_space(1))) u32*)g,
      (__attribute__((address_space(3))) u32*)l, 16, 0, 0);
}

__device__ __forceinline__ int maxi(int x, int y) { return x > y ? x : y; }
__device__ __forceinline__ u32 maxu(u32 x, u32 y) { return x > y ? x : y; }

__device__ __forceinline__ void decode_pair(int t, int& a, int& b) {
  int aa = (int)((129.0 - sqrt(129.0 * 129.0 - 8.0 * (double)t)) * 0.5);
  if (aa < 0) aa = 0;
  if (aa > 63) aa = 63;
  while (((aa + 1) * 64 - ((aa + 1) * aa) / 2) <= t) ++aa;
  while ((aa * 64 - (aa * (aa - 1)) / 2) > t) --aa;
  a = aa;
  b = aa + (t - (aa * 64 - (aa * (aa - 1)) / 2));
}

// ---------- kernel 1: norms + globally-scaled i8 matrix + zero best ----------

__global__ __launch_bounds__(256) void k_normalize(
    const float* __restrict__ x, signed char* __restrict__ xq,
    float* __restrict__ norms, u64* __restrict__ best) {
  const int w = threadIdx.x >> 6, lane = threadIdx.x & 63;
  const int i = blockIdx.x * 4 + w;  // one wave per row
  if (threadIdx.x < 4) best[(size_t)blockIdx.x * 4 + threadIdx.x] = 0;
  const float4* xi = (const float4*)(x + (size_t)i * D);
  float4 v[4];
  float s = 0.f;
#pragma unroll
  for (int t = 0; t < 4; ++t) {
    v[t] = xi[lane + t * 64];
    s += v[t].x * v[t].x + v[t].y * v[t].y + v[t].z * v[t].z + v[t].w * v[t].w;
  }
#pragma unroll
  for (int sh = 32; sh; sh >>= 1) s += __shfl_xor(s, sh, 64);
  const float nrm = sqrtf(s);
  if (lane == 0) norms[i] = nrm;
  const float qs = QSCALE / fmaxf(nrm, EPSF);
  u32* xo = (u32*)(xq + (size_t)i * D);
#pragma unroll
  for (int t = 0; t < 4; ++t) {
    const int q0 = __float2int_rn(fminf(fmaxf(v[t].x * qs, -127.f), 127.f));
    const int q1 = __float2int_rn(fminf(fmaxf(v[t].y * qs, -127.f), 127.f));
    const int q2 = __float2int_rn(fminf(fmaxf(v[t].z * qs, -127.f), 127.f));
    const int q3 = __float2int_rn(fminf(fmaxf(v[t].w * qs, -127.f), 127.f));
    xo[lane + t * 64] = (u32)(q0 & 0xff) | ((u32)(q1 & 0xff) << 8) |
                        ((u32)(q2 & 0xff) << 16) | ((u32)(q3 & 0xff) << 24);
  }
}

// ---------- kernel 2: half-pair tasks, 2 independent blocks per CU ----------
// 512 blocks x 256 thr (4 waves, 2M x 2N; per-wave C = 64x128). Task =
// (pair, half): A rows [a*256+half*128, +128) x B cols [b*256, +256),
// 16 K-tiles of 64 k. Ring-2 LDS (slot = A 8KB + B 16KB, swizzled), 1
// barrier + 1 vmcnt(0) per K-tile. Two independent blocks per CU anti-phase
// (one block's LDS-read burst overlaps the other's MFMA: m114 mechanism).
// Row/col argmax published via deterministic u64 atomicMax.

#define SGB(gaddr, daddr) \
  gload_lds16(xqB + (gaddr) + srcLane, lds + (daddr) + w * 1024)

// stage task K-tile into slot: A 2 chunks + B 4 chunks (6 loads/wave)
#define STG(aG_, bG_, SD_)                      \
  {                                             \
    SGB((aG_), (SD_));                          \
    SGB((aG_) + 65536, (SD_) + 4096);           \
    SGB((bG_), (SD_) + 8192);                   \
    SGB((bG_) + 65536, (SD_) + 12288);          \
    SGB((bG_) + 131072, (SD_) + 16384);         \
    SGB((bG_) + 131072 + 65536, (SD_) + 20480); \
  }

#define KT(T_)                                                                 \
  {                                                                            \
    const int t_ = (T_);                                                       \
    const int tn_ = t_ + 1;                                                    \
    const int ktn_ = tn_ & 15;                                                 \
    const size_t aG = (tn_ >= 16 ? aPanHN : aPanH) + (size_t)(ktn_ * 64) + wG; \
    const size_t bG = (tn_ >= 16 ? bPanN : bPan) + (size_t)(ktn_ * 64) + wG;   \
    __builtin_amdgcn_s_barrier();                                              \
    asm volatile("" ::: "memory");                                             \
    STG(aG, bG, (tn_ & 1) * SLOTB);                                            \
    const int sr = (t_ & 1) * SLOTB;                                           \
    i32x4 aa[4], bb[4];                                                        \
    _Pragma("unroll") for (int m = 0; m < 4; ++m) aa[m] =                      \
        *(const i32x4*)(lds + sr + aOff[m]);                                   \
    _Pragma("unroll") for (int n = 0; n < 4; ++n) bb[n] =                      \
        *(const i32x4*)(lds + sr + 8192 + bOff[n]);                            \
    __builtin_amdgcn_s_setprio(1);                                             \
    _Pragma("unroll") for (int m = 0; m < 4; ++m)                              \
      _Pragma("unroll") for (int n = 0; n < 4; ++n)                            \
        acc[m][n] = __builtin_amdgcn_mfma_i32_16x16x64_i8(aa[m], bb[n],        \
                                                          acc[m][n], 0, 0, 0); \
    __builtin_amdgcn_s_setprio(0);                                             \
    _Pragma("unroll") for (int n = 0; n < 4; ++n) bb[n] =                      \
        *(const i32x4*)(lds + sr + 8192 + bOff[4 + n]);                        \
    __builtin_amdgcn_s_setprio(1);                                             \
    _Pragma("unroll") for (int m = 0; m < 4; ++m)                              \
      _Pragma("unroll") for (int n = 0; n < 4; ++n)                            \
        acc[m][4 + n] = __builtin_amdgcn_mfma_i32_16x16x64_i8(                 \
            aa[m], bb[n], acc[m][4 + n], 0, 0, 0);                             \
    __builtin_amdgcn_s_setprio(0);                                             \
    asm volatile("s_waitcnt vmcnt(0)" ::: "memory");                           \
  }

__global__ __launch_bounds__(256, 2) void k_argmax(
    const signed char* __restrict__ xq, u64* __restrict__ best) {
  extern __shared__ char lds[];
  const char* xqB = (const char*)xq;
  const int tid = (int)threadIdx.x, lane = tid & 63, w = tid >> 6;
  const int wr = w >> 1, wc = w & 1;

  // slot layout: A 128 rows x 64B (8KB) then B 256 rows x 64B (16KB);
  // 2 rows/128B line, granule swizzle inner = (((rr&1)<<6)|(q<<4))^((line&7)<<4)
  int aOff[4], bOff[8];
  const int qh = lane >> 4, li = lane & 15;
#pragma unroll
  for (int m = 0; m < 4; ++m) {
    const int rr = wr * 64 + m * 16 + li;
    const int line = rr >> 1;
    aOff[m] = line * 128 + ((((rr & 1) << 6) | (qh << 4)) ^ ((line & 7) << 4));
  }
#pragma unroll
  for (int nf = 0; nf < 8; ++nf) {
    const int rr = wc * 128 + nf * 16 + li;
    const int line = rr >> 1;
    bOff[nf] = line * 128 + ((((rr & 1) << 6) | (qh << 4)) ^ ((line & 7) << 4));
  }
  // inverse-swizzle per-lane source offset (chunk-invariant; chunk adds 16KB)
  const int posx = (lane & 7) ^ (lane >> 3);
  const int srcLane =
      (((lane >> 3) << 1) | (posx >> 2)) * 1024 + (posx & 3) * 16;
  const size_t wG = (size_t)w * 16384;  // wave's chunk offset in global rows

  const int rB2 = wr * 64 + (qh << 2);
  const int cB2 = wc * 128 + li;

  // static chunk of the task list
  const int t0 = ((int)blockIdx.x * NT) / NBLK;
  const int t1 = (((int)blockIdx.x + 1) * NT) / NBLK;
  int a, b;
  decode_pair(t0 >> 1, a, b);
  int half = t0 & 1;
  size_t aPanH = (size_t)a * PANB + (size_t)half * 131072;
  size_t bPan = (size_t)b * PANB;
  size_t aPanHN = aPanH, bPanN = bPan;

  // prologue: stage tile 0 of first task into slot 0
  STG(aPanH + wG, bPan + wG, 0);
  asm volatile("s_waitcnt vmcnt(0)" ::: "memory");

  i32x4 acc[4][8];
  for (int tt = t0; tt < t1; ++tt) {
    // next task (dup-stage own panels on the last -- staged but never read)
    const int ttn = (tt + 1 < t1) ? tt + 1 : tt;
    int an, bn;
    decode_pair(ttn >> 1, an, bn);
    const int halfn = ttn & 1;
    aPanHN = (size_t)an * PANB + (size_t)halfn * 131072;
    bPanN = (size_t)bn * PANB;

#pragma unroll
    for (int m = 0; m < 4; ++m)
#pragma unroll
      for (int n = 0; n < 8; ++n) acc[m][n] = (i32x4){0, 0, 0, 0};

    for (int kq = 0; kq < 4; ++kq) {
      KT(kq * 4 + 0)
      KT(kq * 4 + 1)
      KT(kq * 4 + 2)
      KT(kq * 4 + 3)
    }

    // ---- epilogue: packed folds, u64 atomicMax publish ----
    const int aBaseH = a * 256 + half * 128;  // this block's 128 rows
    const int colBase = b * 256;
    // row-side: u32 pack ((dot+2^24)<<7)|(nf<<4|li), unsigned fold
#pragma unroll
    for (int m = 0; m < 4; ++m)
#pragma unroll
      for (int r = 0; r < 4; ++r) {
        const int rl = rB2 + m * 16 + r;
        u32 pk = 0;
        if (a == b) {
          const int rg = half * 128 + rl;  // row within the 256 pair rows
#pragma unroll
          for (int nf = 0; nf < 8; ++nf) {
            u32 v = (((u32)acc[m][nf][r] + BIAS) << 7) | (u32)((nf << 4) | li);
            if (rg == cB2 + nf * 16) v = 0;
            pk = maxu(pk, v);
          }
        } else {
#pragma unroll
          for (int nf = 0; nf < 8; ++nf) {
            const u32 v =
                (((u32)acc[m][nf][r] + BIAS) << 7) | (u32)((nf << 4) | li);
            pk = maxu(pk, v);
          }
        }
#pragma unroll
        for (int sh = 1; sh < 16; sh <<= 1)
          pk = maxu(pk, (u32)__shfl_xor((int)pk, sh, 64));
        if (li == 0) {
          const int dot = (int)(pk >> 7) - (int)BIAS;
          const int col = colBase + wc * 128 + (int)(pk & 127u);
          const u64 key = ((u64)((u32)dot ^ 0x80000000u) << 32) | (u32)col;
          atomicMax(best + (aBaseH + rl), key);
        }
      }

    // col-side: rows of b, candidates = this block's 128 a-rows (skip diag)
    if (a != b) {
#pragma unroll
      for (int nf = 0; nf < 8; ++nf) {
        int pk = 0;
#pragma unroll
        for (int m = 0; m < 4; ++m)
#pragma unroll
          for (int r = 0; r < 4; ++r) {
            const int v = (int)((((u32)acc[m][nf][r] + BIAS) << 6) |
                                (u32)(m * 16 + qh * 4 + r));
            pk = maxi(pk, v);
          }
        pk = maxi(pk, __shfl_xor(pk, 16, 64));
        pk = maxi(pk, __shfl_xor(pk, 32, 64));
        if (qh == 0) {
          const int dot = (int)((((u32)pk) >> 6) - BIAS);
          const int grow = aBaseH + wr * 64 + (pk & 63);
          const u64 key = ((u64)((u32)dot ^ 0x80000000u) << 32) | (u32)grow;
          atomicMax(best + (colBase + cB2 + nf * 16), key);
        }
      }
    }

    a = an;
    b = bn;
    half = halfn;
    aPanH = aPanHN;
    bPan = bPanN;
  }
}

// ---------- kernel 3: exact fp32 distance + log ----------

__global__ __launch_bounds__(256) void k_dist(
    const float* __restrict__ x, const float* __restrict__ norms,
    const u64* __restrict__ best, float* __restrict__ logd) {
  const int w = threadIdx.x >> 6, lane = threadIdx.x & 63;
  const int i = blockIdx.x * 4 + w;
  const u64 p = best[i];
  const int j = (int)(p & 0xffffffffu);
  const float invi = 1.f / fmaxf(norms[i], EPSF);
  const float invj = 1.f / fmaxf(norms[j], EPSF);
  const float4* xi = (const float4*)(x + (size_t)i * D);
  const float4* xj = (const float4*)(x + (size_t)j * D);
  float s = 0.f;
#pragma unroll
  for (int t = 0; t < 4; ++t) {
    const float4 av = xi[lane + t * 64], bv = xj[lane + t * 64];
    float d;
    d = av.x * invi - bv.x * invj + EPSF; s += d * d;
    d = av.y * invi - bv.y * invj + EPSF; s += d * d;
    d = av.z * invi - bv.z * invj + EPSF; s += d * d;
    d = av.w * invi - bv.w * invj + EPSF; s += d * d;
  }
#pragma unroll
  for (int sh = 32; sh; sh >>= 1) s += __shfl_xor(s, sh, 64);
  if (lane == 0) logd[i] = logf(sqrtf(s) + EPSF);
}

// ---------- kernel 4: deterministic fixed-order mean ----------

__global__ __launch_bounds__(256) void k_final(const float* __restrict__ logd,
                                               float* __restrict__ out) {
  __shared__ double red[256];
  double s = 0.0;
  for (int i = threadIdx.x; i < N; i += 256) s += (double)logd[i];
  red[threadIdx.x] = s;
  __syncthreads();
  for (int sh = 128; sh; sh >>= 1) {
    if ((int)threadIdx.x < sh) red[threadIdx.x] += red[threadIdx.x + sh];
    __syncthreads();
  }
  if (threadIdx.x == 0) out[0] = (float)(-red[0] / (double)N);
}

// ---------- launch ----------

extern "C" void kernel_launch(void* const* d_in, const int* in_sizes, int n_in,
                              void* d_out, int out_size, void* d_ws,
                              size_t ws_size, hipStream_t stream) {
  const float* x = (const float*)d_in[0];
  float* out = (float*)d_out;
  char* ws = (char*)d_ws;

  // ws: xq 16MB | norms 64KB | best N*8 = 128KB | logd 64KB
  signed char* xq = (signed char*)ws;
  float* norms = (float*)(ws + 16777216);
  u64* best = (u64*)(ws + 16842752);
  float* logd = (float*)(ws + 16973824);

  k_normalize<<<N / 4, 256, 0, stream>>>(x, xq, norms, best);
  k_argmax<<<NBLK, 256, LDS_TOT, stream>>>(xq, best);
  k_dist<<<N / 4, 256, 0, stream>>>(x, norms, best, logd);
  k_final<<<1, 256, 0, stream>>>(logd, out);
}